// Round 2
// baseline (1276.381 us; speedup 1.0000x reference)
//
#include <hip/hip_runtime.h>
#include <math.h>

constexpr int In = 128, Rn = 36, Cn = 64, Ln = 32, Dn = 512;
constexpr int CH = 64, NCH = 8, ST = 68;   // D-chunk + padded LDS stride (floats)
constexpr float EPSf = 1e-8f, LLSE = 6.0f, LSM = 9.0f, SLOPE = 0.1f;
constexpr int GN = Rn * Rn;                // 1296
constexpr int GOFF = In * GN;              // float offset of caption norms in ws

__device__ __forceinline__ float dot4(float4 a, float4 b) {
  return a.x * b.x + a.y * b.y + a.z * b.z + a.w * b.w;
}

// blocks 0..127: G[i] = img_i . img_i^T (36x36). blocks 128..191: caption sq-norms.
extern "C" __global__ __launch_bounds__(256, 2)
void scan_prep(const float* __restrict__ images, const float* __restrict__ captions,
               float* __restrict__ ws)
{
  __shared__ float sm[Rn * 132];
  const int tid = threadIdx.x;
  if (blockIdx.x < In) {
    const int i = blockIdx.x;
    const float* gi = images + (size_t)i * Rn * Dn;
    float acc[6] = {0.f, 0.f, 0.f, 0.f, 0.f, 0.f};
    for (int ch = 0; ch < 4; ++ch) {
      __syncthreads();
      #pragma unroll
      for (int t = 0; t < 5; ++t) {
        int idx = tid + t * 256;           // 36 rows * 32 float4
        if (idx < Rn * 32) {
          int r = idx >> 5, d4 = idx & 31;
          *reinterpret_cast<float4*>(&sm[r * 132 + d4 * 4]) =
            *reinterpret_cast<const float4*>(gi + r * Dn + ch * 128 + d4 * 4);
        }
      }
      __syncthreads();
      #pragma unroll
      for (int q = 0; q < 6; ++q) {
        int e = tid + q * 256;
        if (e < GN) {
          int r = e / Rn, rp = e - r * Rn;
          float s = 0.f;
          for (int s4 = 0; s4 < 32; ++s4)
            s += dot4(*reinterpret_cast<const float4*>(&sm[r * 132 + s4 * 4]),
                      *reinterpret_cast<const float4*>(&sm[rp * 132 + s4 * 4]));
          acc[q] += s;
        }
      }
    }
    #pragma unroll
    for (int q = 0; q < 6; ++q) {
      int e = tid + q * 256;
      if (e < GN) ws[(size_t)i * GN + e] = acc[q];
    }
  } else {
    const int c = blockIdx.x - In;
    const float* gc = captions + (size_t)c * Ln * Dn;
    const int l = tid >> 3, p = tid & 7;
    float s = 0.f;
    #pragma unroll
    for (int t = 0; t < 16; ++t) {
      float4 v = *reinterpret_cast<const float4*>(gc + l * Dn + p * 64 + t * 4);
      s += dot4(v, v);
    }
    s += __shfl_xor(s, 1, 64); s += __shfl_xor(s, 2, 64); s += __shfl_xor(s, 4, 64);
    if (p == 0) ws[GOFF + c * Ln + l] = s;
  }
}

extern "C" __global__ __launch_bounds__(256, 4)
void scan_main(const float* __restrict__ images, const float* __restrict__ captions,
               const int* __restrict__ cap_lens, const float* __restrict__ ws,
               float* __restrict__ out)
{
  // overlay: staging (img 40*68 + cap 32*68 = 4896 floats) OR spart (4*1152 = 4608)
  __shared__ float ovl[4896];
  __shared__ float sS0[Rn * Ln];     // raw Gram
  __shared__ float sP[Rn * 33];      // leaky/masked, then softmax weights
  __shared__ float sG[Rn * Rn];      // image Gram from ws
  __shared__ float sred[512];
  __shared__ float srown[Rn];
  __shared__ float scn[Ln];

  const int tid = threadIdx.x;
  const int c = blockIdx.x & (Cn - 1);
  const int i = blockIdx.x >> 6;
  const int len = cap_lens[c];

  const float* gimg = images + (size_t)i * Rn * Dn;
  const float* gcap = captions + (size_t)c * Ln * Dn;
  float* simg = ovl;                 // 40 rows (36 real, 4 zero) * ST
  float* scap = ovl + 40 * ST;
  float* spart = ovl;                // after phase 1: [4][36][32]

  // prefetch persistent data (first use is after several syncs)
  for (int t = tid; t < GN; t += 256) sG[t] = ws[(size_t)i * GN + t];
  if (tid < Ln) scn[tid] = ws[GOFF + c * Ln + tid];

  // ---------------- phase 1: S0[r][l] = img[r,:] . cap[l,:], D-chunked -------
  const int dp = tid >> 6, tile = tid & 63;
  const int rt = tile >> 3, lt = tile & 7;

  float acc[5][4];
  #pragma unroll
  for (int j = 0; j < 5; ++j)
    #pragma unroll
    for (int k = 0; k < 4; ++k) acc[j][k] = 0.f;

  for (int ch = 0; ch < NCH; ++ch) {
    #pragma unroll
    for (int t = 0; t < 3; ++t) {          // 40 rows * 16 float4 = 640
      int idx = tid + t * 256;
      if (idx < 640) {
        int r = idx >> 4, d4 = idx & 15;
        float4 v = make_float4(0.f, 0.f, 0.f, 0.f);
        if (r < Rn) v = *reinterpret_cast<const float4*>(gimg + r * Dn + ch * CH + d4 * 4);
        *reinterpret_cast<float4*>(&simg[r * ST + d4 * 4]) = v;
      }
    }
    #pragma unroll
    for (int t = 0; t < 2; ++t) {          // 32 rows * 16 float4 = 512
      int idx = tid + t * 256;
      int l = idx >> 4, d4 = idx & 15;
      *reinterpret_cast<float4*>(&scap[l * ST + d4 * 4]) =
        *reinterpret_cast<const float4*>(gcap + l * Dn + ch * CH + d4 * 4);
    }
    __syncthreads();
    #pragma unroll
    for (int s = 0; s < 4; ++s) {
      const int d = dp * 16 + s * 4;
      float4 a[5], b[4];
      #pragma unroll
      for (int j = 0; j < 5; ++j)
        a[j] = *reinterpret_cast<const float4*>(&simg[(rt + 8 * j) * ST + d]);
      #pragma unroll
      for (int k = 0; k < 4; ++k)
        b[k] = *reinterpret_cast<const float4*>(&scap[(lt + 8 * k) * ST + d]);
      #pragma unroll
      for (int j = 0; j < 5; ++j)
        #pragma unroll
        for (int k = 0; k < 4; ++k)
          acc[j][k] += dot4(a[j], b[k]);
    }
    __syncthreads();                        // staging buffer free for next chunk
  }

  // dump partials into overlay (staging reads all done at last sync)
  #pragma unroll
  for (int j = 0; j < 5; ++j) {
    int r = rt + 8 * j;
    if (r < Rn)
      #pragma unroll
      for (int k = 0; k < 4; ++k)
        spart[dp * 1152 + r * Ln + (lt + 8 * k)] = acc[j][k];
  }
  __syncthreads();

  // ---------------- phase 2: leaky+mask, row l2-norm, softmax over r ----------
  #pragma unroll
  for (int t = 0; t < 5; ++t) {
    int idx = tid + t * 256;
    if (idx < Rn * Ln) {
      int l = idx & 31, r = idx >> 5;
      float s0 = spart[idx] + spart[idx + 1152] + spart[idx + 2304] + spart[idx + 3456];
      sS0[idx] = s0;                        // RAW Gram (pre-leaky) for num[l]
      float s = s0 > 0.f ? s0 : SLOPE * s0;
      if (l >= len) s = 0.f;
      sP[r * 33 + l] = s;
      spart[idx] = s * s;
    }
  }
  __syncthreads();

  if (tid < Rn) {
    float a2 = 0.f;
    #pragma unroll
    for (int l = 0; l < Ln; ++l)
      a2 += spart[tid * Ln + ((l + tid) & 31)];
    srown[tid] = sqrtf(a2) + EPSf;
  }
  __syncthreads();

  if (tid < Ln) {
    const int l = tid;
    float m = -1e30f;
    #pragma unroll
    for (int r = 0; r < Rn; ++r) {
      float z = LSM * sP[r * 33 + l] / srown[r];
      sP[r * 33 + l] = z;
      m = fmaxf(m, z);
    }
    float sum = 0.f;
    #pragma unroll
    for (int r = 0; r < Rn; ++r) {
      float e = expf(sP[r * 33 + l] - m);
      sP[r * 33 + l] = e;
      sum += e;
    }
    float inv = 1.f / sum;
    #pragma unroll
    for (int r = 0; r < Rn; ++r) sP[r * 33 + l] *= inv;
  }
  __syncthreads();

  // ------- phase 3: num[l] = sum_r P*S0 ; wn[l] = P^T G P (no wctx!) ---------
  const int l3 = tid & 31, rg = tid >> 5;   // 8 r-groups x 32 l
  float wnp = 0.f, nump = 0.f;
  #pragma unroll
  for (int k = 0; k < 5; ++k) {
    int r = rg + 8 * k;
    if (r < Rn) {
      float p = sP[r * 33 + l3];
      float v = 0.f;
      #pragma unroll 6
      for (int rp = 0; rp < Rn; ++rp)
        v += sG[r * Rn + rp] * sP[rp * 33 + l3];
      wnp += p * v;
      nump += p * sS0[r * Ln + l3];
    }
  }
  sred[rg * 32 + l3] = wnp;
  sred[256 + rg * 32 + l3] = nump;
  __syncthreads();

  // ---------------- phase 4: cosine + masked LSE over l -----------------------
  if (tid < Ln) {
    float wn = 0.f, num = 0.f;
    #pragma unroll
    for (int g = 0; g < 8; ++g) {
      wn  += sred[g * 32 + tid];
      num += sred[256 + g * 32 + tid];
    }
    wn = fmaxf(wn, 0.f);
    float den = fmaxf(sqrtf(scn[tid]), EPSf) * fmaxf(sqrtf(wn), EPSf);
    float sc = (tid < len) ? (num / den) * LLSE : -INFINITY;
    float m = sc;
    #pragma unroll
    for (int k = 1; k < 32; k <<= 1) m = fmaxf(m, __shfl_xor(m, k, 64));
    float e = expf(sc - m);
    #pragma unroll
    for (int k = 1; k < 32; k <<= 1) e += __shfl_xor(e, k, 64);
    if (tid == 0) out[i * Cn + c] = (m + logf(e)) / LLSE;
  }
}

extern "C" void kernel_launch(void* const* d_in, const int* in_sizes, int n_in,
                              void* d_out, int out_size, void* d_ws, size_t ws_size,
                              hipStream_t stream) {
  const float* images   = (const float*)d_in[0];
  const float* captions = (const float*)d_in[1];
  const int*   cap_lens = (const int*)d_in[2];
  float* out = (float*)d_out;
  float* ws  = (float*)d_ws;
  hipLaunchKernelGGL(scan_prep, dim3(192), dim3(256), 0, stream, images, captions, ws);
  hipLaunchKernelGGL(scan_main, dim3(In * Cn), dim3(256), 0, stream,
                     images, captions, cap_lens, ws, out);
}

// Round 3
// 213.173 us; speedup vs baseline: 5.9875x; 5.9875x over previous
//
#include <hip/hip_runtime.h>
#include <math.h>

constexpr int In = 128, Rn = 36, Cn = 64, Ln = 32, Dn = 512;
constexpr int Mn = In * Rn;              // 4608
constexpr int Nn = Cn * Ln;              // 2048
constexpr size_t S0N   = (size_t)Mn * Nn;              // 9437184 floats
constexpr size_t GIOFF = S0N;                          // image Grams
constexpr size_t CNOFF = S0N + (size_t)In * Rn * Rn;   // caption sq-norms
constexpr size_t WSFLOATS = CNOFF + (size_t)Cn * Ln;
constexpr float EPSf = 1e-8f, LLSE = 6.0f, LSM = 9.0f, SLOPE = 0.1f;

__device__ __forceinline__ float dot4(float4 a, float4 b) {
  return a.x * b.x + a.y * b.y + a.z * b.z + a.w * b.w;
}

// ---------------------------------------------------------------------------
// S0 = images(4608x512) . captions(2048x512)^T  -> ws[0..S0N), fp32
// BM=128, BN=64, BK=16; 256 threads; 8x4 per-thread tile.
// ---------------------------------------------------------------------------
extern "C" __global__ __launch_bounds__(256, 2)
void scan_gemm(const float* __restrict__ A, const float* __restrict__ B,
               float* __restrict__ C)
{
  __shared__ float sa[16 * 132];
  __shared__ float sb[16 * 68];
  const int tid = threadIdx.x;
  const int n0 = blockIdx.x * 64;
  const int m0 = blockIdx.y * 128;
  const int tm = tid >> 4, tn = tid & 15;      // rows tm*8.., cols tn*4..
  const int srow = tid >> 2, kq = tid & 3;     // staging coords

  float acc[8][4];
  #pragma unroll
  for (int x = 0; x < 8; ++x)
    #pragma unroll
    for (int y = 0; y < 4; ++y) acc[x][y] = 0.f;

  for (int k0 = 0; k0 < Dn; k0 += 16) {
    __syncthreads();                           // prior reads done
    #pragma unroll
    for (int h = 0; h < 2; ++h) {              // A: 128 rows x 16 k
      int m = srow + h * 64;
      float4 v = *reinterpret_cast<const float4*>(A + (size_t)(m0 + m) * Dn + k0 + kq * 4);
      sa[(kq * 4 + 0) * 132 + m] = v.x;
      sa[(kq * 4 + 1) * 132 + m] = v.y;
      sa[(kq * 4 + 2) * 132 + m] = v.z;
      sa[(kq * 4 + 3) * 132 + m] = v.w;
    }
    {                                          // B: 64 rows x 16 k
      float4 v = *reinterpret_cast<const float4*>(B + (size_t)(n0 + srow) * Dn + k0 + kq * 4);
      sb[(kq * 4 + 0) * 68 + srow] = v.x;
      sb[(kq * 4 + 1) * 68 + srow] = v.y;
      sb[(kq * 4 + 2) * 68 + srow] = v.z;
      sb[(kq * 4 + 3) * 68 + srow] = v.w;
    }
    __syncthreads();
    #pragma unroll
    for (int kk = 0; kk < 16; ++kk) {
      float4 a0 = *reinterpret_cast<const float4*>(&sa[kk * 132 + tm * 8]);
      float4 a1 = *reinterpret_cast<const float4*>(&sa[kk * 132 + tm * 8 + 4]);
      float4 b0 = *reinterpret_cast<const float4*>(&sb[kk * 68 + tn * 4]);
      float av[8] = {a0.x, a0.y, a0.z, a0.w, a1.x, a1.y, a1.z, a1.w};
      float bv[4] = {b0.x, b0.y, b0.z, b0.w};
      #pragma unroll
      for (int x = 0; x < 8; ++x)
        #pragma unroll
        for (int y = 0; y < 4; ++y)
          acc[x][y] = fmaf(av[x], bv[y], acc[x][y]);
    }
  }
  #pragma unroll
  for (int x = 0; x < 8; ++x) {
    float4 o = make_float4(acc[x][0], acc[x][1], acc[x][2], acc[x][3]);
    *reinterpret_cast<float4*>(C + (size_t)(m0 + tm * 8 + x) * Nn + n0 + tn * 4) = o;
  }
}

// ---------------------------------------------------------------------------
// blocks 0..255: half of G[i] = img_i . img_i^T each (2 blocks/image)
// blocks 256..319: caption sq-norms
// ---------------------------------------------------------------------------
extern "C" __global__ __launch_bounds__(256, 2)
void scan_prep(const float* __restrict__ images, const float* __restrict__ captions,
               float* __restrict__ ws)
{
  __shared__ float sm[Rn * 132];
  const int tid = threadIdx.x;
  if (blockIdx.x < 256) {
    const int i = blockIdx.x >> 1, half = blockIdx.x & 1;
    const float* gi = images + (size_t)i * Rn * Dn;
    float acc[3] = {0.f, 0.f, 0.f};
    for (int ch = 0; ch < 4; ++ch) {
      __syncthreads();
      #pragma unroll
      for (int t = 0; t < 5; ++t) {
        int idx = tid + t * 256;               // 36 rows * 32 float4
        if (idx < Rn * 32) {
          int r = idx >> 5, d4 = idx & 31;
          *reinterpret_cast<float4*>(&sm[r * 132 + d4 * 4]) =
            *reinterpret_cast<const float4*>(gi + r * Dn + ch * 128 + d4 * 4);
        }
      }
      __syncthreads();
      #pragma unroll
      for (int q = 0; q < 3; ++q) {
        int eo = tid + q * 256;
        if (eo < 648) {
          int e = half * 648 + eo;
          int r = e / Rn, rp = e - r * Rn;
          float s = 0.f;
          for (int s4 = 0; s4 < 32; ++s4)
            s += dot4(*reinterpret_cast<const float4*>(&sm[r * 132 + s4 * 4]),
                      *reinterpret_cast<const float4*>(&sm[rp * 132 + s4 * 4]));
          acc[q] += s;
        }
      }
    }
    #pragma unroll
    for (int q = 0; q < 3; ++q) {
      int eo = tid + q * 256;
      if (eo < 648) ws[GIOFF + (size_t)i * (Rn * Rn) + half * 648 + eo] = acc[q];
    }
  } else {
    const int c = blockIdx.x - 256;
    const float* gc = captions + (size_t)c * Ln * Dn;
    const int l = tid >> 3, p = tid & 7;
    float s = 0.f;
    #pragma unroll
    for (int t = 0; t < 16; ++t) {
      float4 v = *reinterpret_cast<const float4*>(gc + l * Dn + p * 64 + t * 4);
      s += dot4(v, v);
    }
    s += __shfl_xor(s, 1, 64); s += __shfl_xor(s, 2, 64); s += __shfl_xor(s, 4, 64);
    if (p == 0) ws[CNOFF + c * Ln + l] = s;
  }
}

// ---------------------------------------------------------------------------
// Per (i,c): phases 2-4 on the precomputed S0 tile. One 256-thread block.
// ---------------------------------------------------------------------------
extern "C" __global__ __launch_bounds__(256, 2)
void scan_main(const float* __restrict__ ws, const int* __restrict__ cap_lens,
               float* __restrict__ out)
{
  __shared__ float sS0[Rn * Ln];     // raw Gram tile
  __shared__ float sP[Rn * 33];      // s, then e (unnormalized softmax)
  __shared__ float sG[Rn * Rn];
  __shared__ float sredA[256];       // partial max, then partial wn
  __shared__ float sredB[256];       // partial exp-sum
  __shared__ float sredC[256];       // partial num
  __shared__ float srown[Rn];
  __shared__ float scn[Ln];

  const int tid = threadIdx.x;
  const int c = blockIdx.x & (Cn - 1);
  const int i = blockIdx.x >> 6;
  const int len = cap_lens[c];
  const float* gS0 = ws + (size_t)(i * Rn) * Nn + c * Ln;

  // ---- load S0 tile (float4), G (float4), cap norms ----
  #pragma unroll
  for (int t = 0; t < 2; ++t) {
    int idx = tid + t * 256;                   // 36 rows * 8 float4
    if (idx < Rn * 8) {
      int r = idx >> 3, q = idx & 7;
      *reinterpret_cast<float4*>(&sS0[r * Ln + q * 4]) =
        *reinterpret_cast<const float4*>(gS0 + (size_t)r * Nn + q * 4);
    }
  }
  #pragma unroll
  for (int t = 0; t < 2; ++t) {
    int idx = tid + t * 256;                   // 324 float4
    if (idx < (Rn * Rn) / 4)
      *reinterpret_cast<float4*>(&sG[idx * 4]) =
        *reinterpret_cast<const float4*>(ws + GIOFF + (size_t)i * (Rn * Rn) + idx * 4);
  }
  if (tid < Ln) scn[tid] = ws[CNOFF + c * Ln + tid];
  __syncthreads();

  // ---- pass A: leaky + mask -> sP ----
  #pragma unroll
  for (int t = 0; t < 5; ++t) {
    int idx = tid + t * 256;
    if (idx < Rn * Ln) {
      int r = idx >> 5, l = idx & 31;
      float s0 = sS0[idx];
      float s = s0 > 0.f ? s0 : SLOPE * s0;
      if (l >= len) s = 0.f;
      sP[r * 33 + l] = s;
    }
  }
  __syncthreads();

  // ---- pass B: row l2-norms (4 lanes per row) ----
  if (tid < 144) {
    int p = tid & 3, r = tid >> 2;
    float a2 = 0.f;
    #pragma unroll
    for (int j = 0; j < 8; ++j) {
      float v = sP[r * 33 + p + 4 * j];
      a2 = fmaf(v, v, a2);
    }
    a2 += __shfl_xor(a2, 1, 64);
    a2 += __shfl_xor(a2, 2, 64);
    if (p == 0) srown[r] = sqrtf(a2) + EPSf;
  }
  __syncthreads();

  // ---- pass C: z in regs, partial max over own 5 r's ----
  const int l = tid & 31, rg = tid >> 5;
  float z[5];
  float pm = -1e30f;
  #pragma unroll
  for (int k = 0; k < 5; ++k) {
    int r = rg + 8 * k;
    if (r < Rn) {
      float zz = LSM * sP[r * 33 + l] / srown[r];
      z[k] = zz;
      pm = fmaxf(pm, zz);
    } else z[k] = -1e30f;
  }
  sredA[tid] = pm;
  __syncthreads();

  // ---- pass D: e = exp(z-m) -> sP, partial sum ----
  float m = -1e30f;
  #pragma unroll
  for (int g = 0; g < 8; ++g) m = fmaxf(m, sredA[g * 32 + l]);
  float es = 0.f;
  #pragma unroll
  for (int k = 0; k < 5; ++k) {
    int r = rg + 8 * k;
    if (r < Rn) {
      float e = expf(z[k] - m);
      sP[r * 33 + l] = e;
      es += e;
    }
  }
  sredB[tid] = es;
  __syncthreads();

  // ---- phase 3: num = e.S0, wn = e^T G e (unnormalized) ----
  float wnp = 0.f, nump = 0.f;
  #pragma unroll
  for (int k = 0; k < 5; ++k) {
    int r = rg + 8 * k;
    if (r < Rn) {
      float e = sP[r * 33 + l];
      float v = 0.f;
      #pragma unroll 6
      for (int rp = 0; rp < Rn; ++rp)
        v = fmaf(sG[r * Rn + rp], sP[rp * 33 + l], v);
      wnp = fmaf(e, v, wnp);
      nump = fmaf(e, sS0[r * Ln + l], nump);
    }
  }
  sredA[tid] = wnp;
  sredC[tid] = nump;
  __syncthreads();

  // ---- phase 4: cosine + masked LSE over l ----
  if (tid < Ln) {
    float esum = 0.f, wn = 0.f, num = 0.f;
    #pragma unroll
    for (int g = 0; g < 8; ++g) {
      esum += sredB[g * 32 + tid];
      wn   += sredA[g * 32 + tid];
      num  += sredC[g * 32 + tid];
    }
    float inv = 1.f / esum;
    num *= inv;
    wn = fmaxf(wn, 0.f) * inv * inv;
    float den = fmaxf(sqrtf(scn[tid]), EPSf) * fmaxf(sqrtf(wn), EPSf);
    float sc = (tid < len) ? (num / den) * LLSE : -INFINITY;
    float mx = sc;
    #pragma unroll
    for (int k = 1; k < 32; k <<= 1) mx = fmaxf(mx, __shfl_xor(mx, k, 64));
    float e = expf(sc - mx);
    #pragma unroll
    for (int k = 1; k < 32; k <<= 1) e += __shfl_xor(e, k, 64);
    if (tid == 0) out[i * Cn + c] = (mx + logf(e)) / LLSE;
  }
}

extern "C" void kernel_launch(void* const* d_in, const int* in_sizes, int n_in,
                              void* d_out, int out_size, void* d_ws, size_t ws_size,
                              hipStream_t stream) {
  const float* images   = (const float*)d_in[0];
  const float* captions = (const float*)d_in[1];
  const int*   cap_lens = (const int*)d_in[2];
  float* out = (float*)d_out;
  float* ws  = (float*)d_ws;
  if (ws_size < WSFLOATS * sizeof(float)) return;   // fail loudly (ws too small)

  hipLaunchKernelGGL(scan_gemm, dim3(Nn / 64, Mn / 128), dim3(256), 0, stream,
                     images, captions, ws);
  hipLaunchKernelGGL(scan_prep, dim3(320), dim3(256), 0, stream,
                     images, captions, ws);
  hipLaunchKernelGGL(scan_main, dim3(In * Cn), dim3(256), 0, stream,
                     ws, cap_lens, out);
}

// Round 4
// 113.453 us; speedup vs baseline: 11.2503x; 1.8789x over previous
//
#include <hip/hip_runtime.h>
#include <math.h>

constexpr int In = 128, Rn = 36, Cn = 64, Ln = 32, Dn = 512;
constexpr int Mn = In * Rn;              // 4608
constexpr int Nn = Cn * Ln;              // 2048
constexpr size_t S0N   = (size_t)Mn * Nn;              // 9437184 floats
constexpr size_t GIOFF = S0N;                          // image Grams
constexpr size_t CNOFF = S0N + (size_t)In * Rn * Rn;   // caption sq-norms
constexpr size_t WSFLOATS = CNOFF + (size_t)Cn * Ln;   // 38.4 MB (known-safe)
constexpr float EPSf = 1e-8f, LLSE = 6.0f, LSM = 9.0f, SLOPE = 0.1f;

using short8 = __attribute__((ext_vector_type(8))) short;
using f32x4  = __attribute__((ext_vector_type(4))) float;

__device__ __forceinline__ float dot4(float4 a, float4 b) {
  return a.x * b.x + a.y * b.y + a.z * b.z + a.w * b.w;
}

__device__ __forceinline__ short f2bf(float x) {     // RNE, no NaN inputs
  union { float f; unsigned u; } v; v.f = x;
  unsigned r = v.u + 0x7fffu + ((v.u >> 16) & 1u);
  return (short)(r >> 16);
}

__device__ __forceinline__ short8 pack8(float4 u, float4 v) {
  short8 s;
  s[0] = f2bf(u.x); s[1] = f2bf(u.y); s[2] = f2bf(u.z); s[3] = f2bf(u.w);
  s[4] = f2bf(v.x); s[5] = f2bf(v.y); s[6] = f2bf(v.z); s[7] = f2bf(v.w);
  return s;
}

// ---------------------------------------------------------------------------
// S0 = images(4608x512) . captions(2048x512)^T -> fp32, via bf16 MFMA.
// 128x128 tile, 4 waves (2x2 of 64x64), BK=32, cast-on-the-fly staging.
// LDS stride 40 bf16 (80 B): 16B-aligned b128 reads, <=2-way conflicts (free).
// ---------------------------------------------------------------------------
extern "C" __global__ __launch_bounds__(256, 2)
void scan_gemm(const float* __restrict__ A, const float* __restrict__ B,
               float* __restrict__ C)
{
  __shared__ short Alds[128 * 40];
  __shared__ short Blds[128 * 40];
  const int tid = threadIdx.x;
  const int n0 = blockIdx.x * 128, m0 = blockIdx.y * 128;
  const int lane = tid & 63, wave = tid >> 6;
  const int wm = wave >> 1, wn = wave & 1;
  const int lr = lane & 15, lk = lane >> 4;
  const int srow = tid >> 1, sh = tid & 1;           // staging: row, 16-col half

  const float* gA = A + (size_t)(m0 + srow) * Dn + sh * 16;
  const float* gB = B + (size_t)(n0 + srow) * Dn + sh * 16;
  short* swA = &Alds[srow * 40 + sh * 16];
  short* swB = &Blds[srow * 40 + sh * 16];
  const short* rA = &Alds[(wm * 64 + lr) * 40 + lk * 8];
  const short* rB = &Blds[(wn * 64 + lr) * 40 + lk * 8];

  f32x4 acc[4][4];
  #pragma unroll
  for (int x = 0; x < 4; ++x)
    #pragma unroll
    for (int y = 0; y < 4; ++y) acc[x][y] = {0.f, 0.f, 0.f, 0.f};

  for (int k0 = 0; k0 < Dn; k0 += 32) {
    float4 a0 = *reinterpret_cast<const float4*>(gA + k0);
    float4 a1 = *reinterpret_cast<const float4*>(gA + k0 + 4);
    float4 a2 = *reinterpret_cast<const float4*>(gA + k0 + 8);
    float4 a3 = *reinterpret_cast<const float4*>(gA + k0 + 12);
    float4 b0 = *reinterpret_cast<const float4*>(gB + k0);
    float4 b1 = *reinterpret_cast<const float4*>(gB + k0 + 4);
    float4 b2 = *reinterpret_cast<const float4*>(gB + k0 + 8);
    float4 b3 = *reinterpret_cast<const float4*>(gB + k0 + 12);
    __syncthreads();                       // prior K-step's ds_reads done
    *reinterpret_cast<short8*>(swA)     = pack8(a0, a1);
    *reinterpret_cast<short8*>(swA + 8) = pack8(a2, a3);
    *reinterpret_cast<short8*>(swB)     = pack8(b0, b1);
    *reinterpret_cast<short8*>(swB + 8) = pack8(b2, b3);
    __syncthreads();
    short8 af[4], bf[4];
    #pragma unroll
    for (int x = 0; x < 4; ++x) af[x] = *reinterpret_cast<const short8*>(rA + x * 16 * 40);
    #pragma unroll
    for (int y = 0; y < 4; ++y) bf[y] = *reinterpret_cast<const short8*>(rB + y * 16 * 40);
    #pragma unroll
    for (int x = 0; x < 4; ++x)
      #pragma unroll
      for (int y = 0; y < 4; ++y)
        acc[x][y] = __builtin_amdgcn_mfma_f32_16x16x32_bf16(af[x], bf[y], acc[x][y], 0, 0, 0);
  }

  // epilogue: C/D layout col=lane&15, row=(lane>>4)*4+j  [m89-verified]
  const int orow = m0 + wm * 64 + lk * 4;
  const int ocol = n0 + wn * 64 + lr;
  #pragma unroll
  for (int x = 0; x < 4; ++x)
    #pragma unroll
    for (int y = 0; y < 4; ++y)
      #pragma unroll
      for (int j = 0; j < 4; ++j)
        C[(size_t)(orow + x * 16 + j) * Nn + ocol + y * 16] = acc[x][y][j];
}

// ---------------------------------------------------------------------------
// blocks 0..255: half of G[i] = img_i . img_i^T each. blocks 256..319: cap norms
// ---------------------------------------------------------------------------
extern "C" __global__ __launch_bounds__(256, 2)
void scan_prep(const float* __restrict__ images, const float* __restrict__ captions,
               float* __restrict__ ws)
{
  __shared__ float sm[Rn * 132];
  const int tid = threadIdx.x;
  if (blockIdx.x < 256) {
    const int i = blockIdx.x >> 1, half = blockIdx.x & 1;
    const float* gi = images + (size_t)i * Rn * Dn;
    float acc[3] = {0.f, 0.f, 0.f};
    for (int ch = 0; ch < 4; ++ch) {
      __syncthreads();
      #pragma unroll
      for (int t = 0; t < 5; ++t) {
        int idx = tid + t * 256;
        if (idx < Rn * 32) {
          int r = idx >> 5, d4 = idx & 31;
          *reinterpret_cast<float4*>(&sm[r * 132 + d4 * 4]) =
            *reinterpret_cast<const float4*>(gi + r * Dn + ch * 128 + d4 * 4);
        }
      }
      __syncthreads();
      #pragma unroll
      for (int q = 0; q < 3; ++q) {
        int eo = tid + q * 256;
        if (eo < 648) {
          int e = half * 648 + eo;
          int r = e / Rn, rp = e - r * Rn;
          float s = 0.f;
          for (int s4 = 0; s4 < 32; ++s4)
            s += dot4(*reinterpret_cast<const float4*>(&sm[r * 132 + s4 * 4]),
                      *reinterpret_cast<const float4*>(&sm[rp * 132 + s4 * 4]));
          acc[q] += s;
        }
      }
    }
    #pragma unroll
    for (int q = 0; q < 3; ++q) {
      int eo = tid + q * 256;
      if (eo < 648) ws[GIOFF + (size_t)i * (Rn * Rn) + half * 648 + eo] = acc[q];
    }
  } else {
    const int c = blockIdx.x - 256;
    const float* gc = captions + (size_t)c * Ln * Dn;
    const int l = tid >> 3, p = tid & 7;
    float s = 0.f;
    #pragma unroll
    for (int t = 0; t < 16; ++t) {
      float4 v = *reinterpret_cast<const float4*>(gc + l * Dn + p * 64 + t * 4);
      s += dot4(v, v);
    }
    s += __shfl_xor(s, 1, 64); s += __shfl_xor(s, 2, 64); s += __shfl_xor(s, 4, 64);
    if (p == 0) ws[CNOFF + c * Ln + l] = s;
  }
}

// ---------------------------------------------------------------------------
// Per (i,c): phases 2-4 on the precomputed S0 tile. One 256-thread block.
// ---------------------------------------------------------------------------
extern "C" __global__ __launch_bounds__(256, 2)
void scan_main(const float* __restrict__ ws, const int* __restrict__ cap_lens,
               float* __restrict__ out)
{
  __shared__ float sS0[Rn * Ln];
  __shared__ float sP[Rn * 33];
  __shared__ float sG[Rn * Rn];
  __shared__ float sredA[256];
  __shared__ float sredB[256];
  __shared__ float sredC[256];
  __shared__ float srown[Rn];
  __shared__ float scn[Ln];

  const int tid = threadIdx.x;
  const int c = blockIdx.x & (Cn - 1);
  const int i = blockIdx.x >> 6;
  const int len = cap_lens[c];
  const float* gS0 = ws + (size_t)(i * Rn) * Nn + c * Ln;

  #pragma unroll
  for (int t = 0; t < 2; ++t) {
    int idx = tid + t * 256;
    if (idx < Rn * 8) {
      int r = idx >> 3, q = idx & 7;
      *reinterpret_cast<float4*>(&sS0[r * Ln + q * 4]) =
        *reinterpret_cast<const float4*>(gS0 + (size_t)r * Nn + q * 4);
    }
  }
  #pragma unroll
  for (int t = 0; t < 2; ++t) {
    int idx = tid + t * 256;
    if (idx < (Rn * Rn) / 4)
      *reinterpret_cast<float4*>(&sG[idx * 4]) =
        *reinterpret_cast<const float4*>(ws + GIOFF + (size_t)i * (Rn * Rn) + idx * 4);
  }
  if (tid < Ln) scn[tid] = ws[CNOFF + c * Ln + tid];
  __syncthreads();

  #pragma unroll
  for (int t = 0; t < 5; ++t) {
    int idx = tid + t * 256;
    if (idx < Rn * Ln) {
      int r = idx >> 5, l = idx & 31;
      float s0 = sS0[idx];
      float s = s0 > 0.f ? s0 : SLOPE * s0;
      if (l >= len) s = 0.f;
      sP[r * 33 + l] = s;
    }
  }
  __syncthreads();

  if (tid < 144) {
    int p = tid & 3, r = tid >> 2;
    float a2 = 0.f;
    #pragma unroll
    for (int j = 0; j < 8; ++j) {
      float v = sP[r * 33 + p + 4 * j];
      a2 = fmaf(v, v, a2);
    }
    a2 += __shfl_xor(a2, 1, 64);
    a2 += __shfl_xor(a2, 2, 64);
    if (p == 0) srown[r] = sqrtf(a2) + EPSf;
  }
  __syncthreads();

  const int l = tid & 31, rg = tid >> 5;
  float z[5];
  float pm = -1e30f;
  #pragma unroll
  for (int k = 0; k < 5; ++k) {
    int r = rg + 8 * k;
    if (r < Rn) {
      float zz = LSM * sP[r * 33 + l] / srown[r];
      z[k] = zz;
      pm = fmaxf(pm, zz);
    } else z[k] = -1e30f;
  }
  sredA[tid] = pm;
  __syncthreads();

  float m = -1e30f;
  #pragma unroll
  for (int g = 0; g < 8; ++g) m = fmaxf(m, sredA[g * 32 + l]);
  float es = 0.f;
  #pragma unroll
  for (int k = 0; k < 5; ++k) {
    int r = rg + 8 * k;
    if (r < Rn) {
      float e = expf(z[k] - m);
      sP[r * 33 + l] = e;
      es += e;
    }
  }
  sredB[tid] = es;
  __syncthreads();

  float wnp = 0.f, nump = 0.f;
  #pragma unroll
  for (int k = 0; k < 5; ++k) {
    int r = rg + 8 * k;
    if (r < Rn) {
      float e = sP[r * 33 + l];
      float v = 0.f;
      #pragma unroll 6
      for (int rp = 0; rp < Rn; ++rp)
        v = fmaf(sG[r * Rn + rp], sP[rp * 33 + l], v);
      wnp = fmaf(e, v, wnp);
      nump = fmaf(e, sS0[r * Ln + l], nump);
    }
  }
  sredA[tid] = wnp;
  sredC[tid] = nump;
  __syncthreads();

  if (tid < Ln) {
    float esum = 0.f, wn = 0.f, num = 0.f;
    #pragma unroll
    for (int g = 0; g < 8; ++g) {
      esum += sredB[g * 32 + tid];
      wn   += sredA[g * 32 + tid];
      num  += sredC[g * 32 + tid];
    }
    float inv = 1.f / esum;
    num *= inv;
    wn = fmaxf(wn, 0.f) * inv * inv;
    float den = fmaxf(sqrtf(scn[tid]), EPSf) * fmaxf(sqrtf(wn), EPSf);
    float sc = (tid < len) ? (num / den) * LLSE : -INFINITY;
    float mx = sc;
    #pragma unroll
    for (int k = 1; k < 32; k <<= 1) mx = fmaxf(mx, __shfl_xor(mx, k, 64));
    float e = expf(sc - mx);
    #pragma unroll
    for (int k = 1; k < 32; k <<= 1) e += __shfl_xor(e, k, 64);
    if (tid == 0) out[i * Cn + c] = (mx + logf(e)) / LLSE;
  }
}

extern "C" void kernel_launch(void* const* d_in, const int* in_sizes, int n_in,
                              void* d_out, int out_size, void* d_ws, size_t ws_size,
                              hipStream_t stream) {
  const float* images   = (const float*)d_in[0];
  const float* captions = (const float*)d_in[1];
  const int*   cap_lens = (const int*)d_in[2];
  float* out = (float*)d_out;
  float* ws  = (float*)d_ws;
  if (ws_size < WSFLOATS * sizeof(float)) return;

  hipLaunchKernelGGL(scan_gemm, dim3(Nn / 128, Mn / 128), dim3(256), 0, stream,
                     images, captions, ws);
  hipLaunchKernelGGL(scan_prep, dim3(320), dim3(256), 0, stream,
                     images, captions, ws);
  hipLaunchKernelGGL(scan_main, dim3(In * Cn), dim3(256), 0, stream,
                     ws, cap_lens, out);
}

// Round 5
// 89.970 us; speedup vs baseline: 14.1868x; 1.2610x over previous
//
#include <hip/hip_runtime.h>
#include <math.h>

constexpr int In = 128, Rn = 36, Cn = 64, Ln = 32, Dn = 512;
constexpr int Mn = In * Rn;              // 4608
constexpr int Nn = Cn * Ln;              // 2048
constexpr size_t S0N   = (size_t)Mn * Nn;              // 9437184 floats
constexpr size_t GB_F  = (size_t)In * 48 * 64 * 2 / 4; // Gb bf16 region in floats (196608)
constexpr size_t CNOFF = S0N + GB_F;                   // caption sq-norms (floats)
constexpr size_t WSFLOATS = CNOFF + (size_t)Cn * Ln;   // ~38.55 MB
constexpr float EPSf = 1e-8f, LLSE = 6.0f, LSM = 9.0f, SLOPE = 0.1f;

using short8 = __attribute__((ext_vector_type(8))) short;
using f32x4  = __attribute__((ext_vector_type(4))) float;

__device__ __forceinline__ float dot4(float4 a, float4 b) {
  return a.x * b.x + a.y * b.y + a.z * b.z + a.w * b.w;
}

__device__ __forceinline__ unsigned short f2bf(float x) {   // RNE
  union { float f; unsigned u; } v; v.f = x;
  unsigned r = v.u + 0x7fffu + ((v.u >> 16) & 1u);
  return (unsigned short)(r >> 16);
}

__device__ __forceinline__ float bf2f(unsigned short u) {
  union { unsigned uu; float ff; } cv; cv.uu = ((unsigned)u) << 16;
  return cv.ff;
}

__device__ __forceinline__ short8 pack8(float4 u, float4 v) {
  short8 s;
  s[0] = (short)f2bf(u.x); s[1] = (short)f2bf(u.y); s[2] = (short)f2bf(u.z); s[3] = (short)f2bf(u.w);
  s[4] = (short)f2bf(v.x); s[5] = (short)f2bf(v.y); s[6] = (short)f2bf(v.z); s[7] = (short)f2bf(v.w);
  return s;
}

// ---------------------------------------------------------------------------
// S0 = images(4608x512) . captions(2048x512)^T -> fp32, via bf16 MFMA.
// (unchanged from round 4 — passed at absmax 0.0039)
// ---------------------------------------------------------------------------
extern "C" __global__ __launch_bounds__(256, 2)
void scan_gemm(const float* __restrict__ A, const float* __restrict__ B,
               float* __restrict__ C)
{
  __shared__ short Alds[128 * 40];
  __shared__ short Blds[128 * 40];
  const int tid = threadIdx.x;
  const int n0 = blockIdx.x * 128, m0 = blockIdx.y * 128;
  const int lane = tid & 63, wave = tid >> 6;
  const int wm = wave >> 1, wn = wave & 1;
  const int lr = lane & 15, lk = lane >> 4;
  const int srow = tid >> 1, sh = tid & 1;

  const float* gA = A + (size_t)(m0 + srow) * Dn + sh * 16;
  const float* gB = B + (size_t)(n0 + srow) * Dn + sh * 16;
  short* swA = &Alds[srow * 40 + sh * 16];
  short* swB = &Blds[srow * 40 + sh * 16];
  const short* rA = &Alds[(wm * 64 + lr) * 40 + lk * 8];
  const short* rB = &Blds[(wn * 64 + lr) * 40 + lk * 8];

  f32x4 acc[4][4];
  #pragma unroll
  for (int x = 0; x < 4; ++x)
    #pragma unroll
    for (int y = 0; y < 4; ++y) acc[x][y] = {0.f, 0.f, 0.f, 0.f};

  for (int k0 = 0; k0 < Dn; k0 += 32) {
    float4 a0 = *reinterpret_cast<const float4*>(gA + k0);
    float4 a1 = *reinterpret_cast<const float4*>(gA + k0 + 4);
    float4 a2 = *reinterpret_cast<const float4*>(gA + k0 + 8);
    float4 a3 = *reinterpret_cast<const float4*>(gA + k0 + 12);
    float4 b0 = *reinterpret_cast<const float4*>(gB + k0);
    float4 b1 = *reinterpret_cast<const float4*>(gB + k0 + 4);
    float4 b2 = *reinterpret_cast<const float4*>(gB + k0 + 8);
    float4 b3 = *reinterpret_cast<const float4*>(gB + k0 + 12);
    __syncthreads();
    *reinterpret_cast<short8*>(swA)     = pack8(a0, a1);
    *reinterpret_cast<short8*>(swA + 8) = pack8(a2, a3);
    *reinterpret_cast<short8*>(swB)     = pack8(b0, b1);
    *reinterpret_cast<short8*>(swB + 8) = pack8(b2, b3);
    __syncthreads();
    short8 af[4], bf[4];
    #pragma unroll
    for (int x = 0; x < 4; ++x) af[x] = *reinterpret_cast<const short8*>(rA + x * 16 * 40);
    #pragma unroll
    for (int y = 0; y < 4; ++y) bf[y] = *reinterpret_cast<const short8*>(rB + y * 16 * 40);
    #pragma unroll
    for (int x = 0; x < 4; ++x)
      #pragma unroll
      for (int y = 0; y < 4; ++y)
        acc[x][y] = __builtin_amdgcn_mfma_f32_16x16x32_bf16(af[x], bf[y], acc[x][y], 0, 0, 0);
  }

  const int orow = m0 + wm * 64 + lk * 4;
  const int ocol = n0 + wn * 64 + lr;
  #pragma unroll
  for (int x = 0; x < 4; ++x)
    #pragma unroll
    for (int y = 0; y < 4; ++y)
      #pragma unroll
      for (int j = 0; j < 4; ++j)
        C[(size_t)(orow + x * 16 + j) * Nn + ocol + y * 16] = acc[x][y][j];
}

// ---------------------------------------------------------------------------
// blocks 0..255: half of G[i] = img_i.img_i^T, stored bf16 padded [48][64].
// blocks 256..319: caption sq-norms.
// ---------------------------------------------------------------------------
extern "C" __global__ __launch_bounds__(256, 2)
void scan_prep(const float* __restrict__ images, const float* __restrict__ captions,
               float* __restrict__ ws)
{
  __shared__ float sm[Rn * 132];
  const int tid = threadIdx.x;
  unsigned short* GbAll = (unsigned short*)(ws + S0N);
  if (blockIdx.x < 256) {
    const int i = blockIdx.x >> 1, half = blockIdx.x & 1;
    const float* gi = images + (size_t)i * Rn * Dn;
    unsigned short* gb = GbAll + (size_t)i * 48 * 64;
    float acc[3] = {0.f, 0.f, 0.f};
    for (int ch = 0; ch < 4; ++ch) {
      __syncthreads();
      #pragma unroll
      for (int t = 0; t < 5; ++t) {
        int idx = tid + t * 256;
        if (idx < Rn * 32) {
          int r = idx >> 5, d4 = idx & 31;
          *reinterpret_cast<float4*>(&sm[r * 132 + d4 * 4]) =
            *reinterpret_cast<const float4*>(gi + r * Dn + ch * 128 + d4 * 4);
        }
      }
      __syncthreads();
      #pragma unroll
      for (int q = 0; q < 3; ++q) {
        int eo = tid + q * 256;
        if (eo < 648) {
          int e = half * 648 + eo;
          int r = e / Rn, rp = e - r * Rn;
          float s = 0.f;
          for (int s4 = 0; s4 < 32; ++s4)
            s += dot4(*reinterpret_cast<const float4*>(&sm[r * 132 + s4 * 4]),
                      *reinterpret_cast<const float4*>(&sm[rp * 132 + s4 * 4]));
          acc[q] += s;
        }
      }
    }
    #pragma unroll
    for (int q = 0; q < 3; ++q) {
      int eo = tid + q * 256;
      if (eo < 648) {
        int e = half * 648 + eo;
        int r = e / Rn, rp = e - r * Rn;
        gb[r * 64 + rp] = f2bf(acc[q]);
      }
    }
    // zero padding: this half zeros cols 36..63 of its 18 rows + 6 tail rows
    for (int idx = tid; idx < 18 * 28; idx += 256) {
      int rr = half * 18 + idx / 28, cc = 36 + idx % 28;
      gb[rr * 64 + cc] = 0;
    }
    for (int idx = tid; idx < 6 * 64; idx += 256) {
      int rr = 36 + half * 6 + (idx >> 6);
      gb[rr * 64 + (idx & 63)] = 0;
    }
  } else {
    const int c = blockIdx.x - 256;
    const float* gc = captions + (size_t)c * Ln * Dn;
    const int l = tid >> 3, p = tid & 7;
    float s = 0.f;
    #pragma unroll
    for (int t = 0; t < 16; ++t) {
      float4 v = *reinterpret_cast<const float4*>(gc + l * Dn + p * 64 + t * 4);
      s += dot4(v, v);
    }
    s += __shfl_xor(s, 1, 64); s += __shfl_xor(s, 2, 64); s += __shfl_xor(s, 4, 64);
    if (p == 0) ws[CNOFF + c * Ln + l] = s;
  }
}

// ---------------------------------------------------------------------------
// Per (i,c): leaky/mask/norm/softmax, then wn = e^T G e via MFMA (V = Gb.E),
// num/esum fused into the exp pass. One 256-thread block.
// ---------------------------------------------------------------------------
extern "C" __global__ __launch_bounds__(256, 2)
void scan_main(const float* __restrict__ ws, const int* __restrict__ cap_lens,
               float* __restrict__ out)
{
  __shared__ float sS0[Rn * Ln];           // raw S0 tile
  __shared__ float sP[Rn * 33];            // leaky-masked s
  __shared__ unsigned short sET[32 * 72];  // e bf16, [l][r], K-padded to 64
  __shared__ float sredA[256];
  __shared__ float sredB[256];
  __shared__ float sredC[256];
  __shared__ float sredW[4][20];
  __shared__ float srown[Rn];
  __shared__ float scn[Ln];

  const int tid = threadIdx.x;
  const int c = blockIdx.x & (Cn - 1);
  const int i = blockIdx.x >> 6;
  const int len = cap_lens[c];
  const float* gS0 = ws + (size_t)(i * Rn) * Nn + c * Ln;
  const unsigned short* Gb = (const unsigned short*)(ws + S0N) + (size_t)i * 48 * 64;

  // ---- loads + sET zero-init ----
  #pragma unroll
  for (int t = 0; t < 2; ++t) {
    int idx = tid + t * 256;
    if (idx < Rn * 8) {
      int r = idx >> 3, q = idx & 7;
      *reinterpret_cast<float4*>(&sS0[r * Ln + q * 4]) =
        *reinterpret_cast<const float4*>(gS0 + (size_t)r * Nn + q * 4);
    }
  }
  for (int idx = tid; idx < (32 * 72) / 2; idx += 256)
    reinterpret_cast<unsigned*>(sET)[idx] = 0;
  if (tid < Ln) scn[tid] = ws[CNOFF + c * Ln + tid];
  __syncthreads();

  // ---- pass A: leaky + mask -> sP ----
  #pragma unroll
  for (int t = 0; t < 5; ++t) {
    int idx = tid + t * 256;
    if (idx < Rn * Ln) {
      int r = idx >> 5, l = idx & 31;
      float s0 = sS0[idx];
      float s = s0 > 0.f ? s0 : SLOPE * s0;
      if (l >= len) s = 0.f;
      sP[r * 33 + l] = s;
    }
  }
  __syncthreads();

  // ---- pass B: row l2-norms ----
  if (tid < 144) {
    int p = tid & 3, r = tid >> 2;
    float a2 = 0.f;
    #pragma unroll
    for (int j = 0; j < 8; ++j) {
      float v = sP[r * 33 + p + 4 * j];
      a2 = fmaf(v, v, a2);
    }
    a2 += __shfl_xor(a2, 1, 64);
    a2 += __shfl_xor(a2, 2, 64);
    if (p == 0) srown[r] = sqrtf(a2) + EPSf;
  }
  __syncthreads();

  // ---- pass C: z in regs + partial max ----
  const int l = tid & 31, rg = tid >> 5;
  float z[5];
  float pm = -1e30f;
  #pragma unroll
  for (int k = 0; k < 5; ++k) {
    int r = rg + 8 * k;
    if (r < Rn) {
      float zz = LSM * sP[r * 33 + l] / srown[r];
      z[k] = zz;
      pm = fmaxf(pm, zz);
    } else z[k] = -1e30f;
  }
  sredA[tid] = pm;
  __syncthreads();

  // ---- pass D: e = exp(z-m); fused esum/num; e -> sET (bf16, transposed) ----
  float m = -1e30f;
  #pragma unroll
  for (int g = 0; g < 8; ++g) m = fmaxf(m, sredA[g * 32 + l]);
  float es = 0.f, nump = 0.f;
  #pragma unroll
  for (int k = 0; k < 5; ++k) {
    int r = rg + 8 * k;
    if (r < Rn) {
      float e = expf(z[k] - m);
      es += e;
      nump = fmaf(e, sS0[r * Ln + l], nump);
      sET[l * 72 + r] = f2bf(e);
    }
  }
  sredB[tid] = es;
  sredC[tid] = nump;
  __syncthreads();

  // ---- wn via MFMA: V = G.E ; wn[l] = sum_r E[r][l]*V[r][l] ----
  {
    const int lane = tid & 63, wv = tid >> 6;
    const int lr = lane & 15, lk = lane >> 4;
    const int nt = wv & 1;
    const unsigned short* bcol = &sET[(nt * 16 + lr) * 72];
    float wnp = 0.f;
    const int nm = (wv >> 1) ? 1 : 2;        // waves 0,1: m={0,2}; waves 2,3: m={1}
    for (int t = 0; t < nm; ++t) {
      const int mt = (wv >> 1) ? 1 : (t == 0 ? 0 : 2);
      f32x4 acc = {0.f, 0.f, 0.f, 0.f};
      #pragma unroll
      for (int ks = 0; ks < 2; ++ks) {
        short8 afr = *reinterpret_cast<const short8*>(Gb + (mt * 16 + lr) * 64 + ks * 32 + lk * 8);
        short8 bfr = *reinterpret_cast<const short8*>(bcol + ks * 32 + lk * 8);
        acc = __builtin_amdgcn_mfma_f32_16x16x32_bf16(afr, bfr, acc, 0, 0, 0);
      }
      #pragma unroll
      for (int j = 0; j < 4; ++j) {
        int row = mt * 16 + lk * 4 + j;
        if (row < Rn) wnp = fmaf(acc[j], bf2f(bcol[row]), wnp);
      }
    }
    wnp += __shfl_xor(wnp, 16, 64);
    wnp += __shfl_xor(wnp, 32, 64);
    if (lk == 0) sredW[wv][lr] = wnp;
  }
  __syncthreads();

  // ---- phase 4: cosine + masked LSE over l ----
  if (tid < Ln) {
    float esum = 0.f, num = 0.f;
    #pragma unroll
    for (int g = 0; g < 8; ++g) {
      esum += sredB[g * 32 + tid];
      num  += sredC[g * 32 + tid];
    }
    float wn = (tid < 16) ? (sredW[0][tid] + sredW[2][tid])
                          : (sredW[1][tid - 16] + sredW[3][tid - 16]);
    float inv = 1.f / esum;
    num *= inv;
    wn = fmaxf(wn, 0.f) * inv * inv;
    float den = fmaxf(sqrtf(scn[tid]), EPSf) * fmaxf(sqrtf(wn), EPSf);
    float sc = (tid < len) ? (num / den) * LLSE : -INFINITY;
    float mx = sc;
    #pragma unroll
    for (int k = 1; k < 32; k <<= 1) mx = fmaxf(mx, __shfl_xor(mx, k, 64));
    float e = expf(sc - mx);
    #pragma unroll
    for (int k = 1; k < 32; k <<= 1) e += __shfl_xor(e, k, 64);
    if (tid == 0) out[i * Cn + c] = (mx + logf(e)) / LLSE;
  }
}

extern "C" void kernel_launch(void* const* d_in, const int* in_sizes, int n_in,
                              void* d_out, int out_size, void* d_ws, size_t ws_size,
                              hipStream_t stream) {
  const float* images   = (const float*)d_in[0];
  const float* captions = (const float*)d_in[1];
  const int*   cap_lens = (const int*)d_in[2];
  float* out = (float*)d_out;
  float* ws  = (float*)d_ws;
  if (ws_size < WSFLOATS * sizeof(float)) return;

  hipLaunchKernelGGL(scan_gemm, dim3(Nn / 128, Mn / 128), dim3(256), 0, stream,
                     images, captions, ws);
  hipLaunchKernelGGL(scan_prep, dim3(320), dim3(256), 0, stream,
                     images, captions, ws);
  hipLaunchKernelGGL(scan_main, dim3(In * Cn), dim3(256), 0, stream,
                     ws, cap_lens, out);
}

// Round 6
// 77.145 us; speedup vs baseline: 16.5453x; 1.1663x over previous
//
#include <hip/hip_runtime.h>
#include <math.h>

constexpr int In = 128, Rn = 36, Cn = 64, Ln = 32, Dn = 512;
constexpr int Mn = In * Rn;              // 4608
constexpr int Nn = Cn * Ln;              // 2048
constexpr size_t S0N   = (size_t)Mn * Nn;                // 9437184 floats
constexpr size_t ABOFF = S0N;                            // images bf16 (elems Mn*Dn)
constexpr size_t BBOFF = ABOFF + (size_t)Mn * Dn / 2;    // captions bf16
constexpr size_t GBOFF = BBOFF + (size_t)Nn * Dn / 2;    // Gb bf16 [In][48][64]
constexpr size_t CNOFF = GBOFF + (size_t)In * 48 * 64 / 2;
constexpr size_t WSFLOATS = CNOFF + (size_t)Cn * Ln;
constexpr float EPSf = 1e-8f, LLSE = 6.0f, LSM = 9.0f, SLOPE = 0.1f;

using short8 = __attribute__((ext_vector_type(8))) short;
using f32x4  = __attribute__((ext_vector_type(4))) float;

__device__ __forceinline__ float dot4(float4 a, float4 b) {
  return a.x * b.x + a.y * b.y + a.z * b.z + a.w * b.w;
}

__device__ __forceinline__ unsigned short f2bf(float x) {   // RNE
  union { float f; unsigned u; } v; v.f = x;
  unsigned r = v.u + 0x7fffu + ((v.u >> 16) & 1u);
  return (unsigned short)(r >> 16);
}

__device__ __forceinline__ float bf2f(unsigned short u) {
  union { unsigned uu; float ff; } cv; cv.uu = ((unsigned)u) << 16;
  return cv.ff;
}

__device__ __forceinline__ short8 pack8(float4 u, float4 v) {
  short8 s;
  s[0] = (short)f2bf(u.x); s[1] = (short)f2bf(u.y); s[2] = (short)f2bf(u.z); s[3] = (short)f2bf(u.w);
  s[4] = (short)f2bf(v.x); s[5] = (short)f2bf(v.y); s[6] = (short)f2bf(v.z); s[7] = (short)f2bf(v.w);
  return s;
}

// ---------------------------------------------------------------------------
// fp32 -> bf16 one-shot conversion of images+captions into ws.
// 425984 chunks of 8 elements; grid 1664 x 256 exactly.
// ---------------------------------------------------------------------------
extern "C" __global__ __launch_bounds__(256, 2)
void scan_cvt(const float* __restrict__ imgs, const float* __restrict__ caps,
              float* __restrict__ ws)
{
  const int chunk = blockIdx.x * 256 + threadIdx.x;
  const float* src;
  unsigned short* dst;
  size_t off;
  if (chunk < (Mn * Dn) / 8) {
    src = imgs; dst = (unsigned short*)(ws + ABOFF); off = (size_t)chunk * 8;
  } else {
    src = caps; dst = (unsigned short*)(ws + BBOFF);
    off = (size_t)(chunk - (Mn * Dn) / 8) * 8;
  }
  float4 u = *reinterpret_cast<const float4*>(src + off);
  float4 v = *reinterpret_cast<const float4*>(src + off + 4);
  *reinterpret_cast<short8*>(dst + off) = pack8(u, v);
}

// ---------------------------------------------------------------------------
// S0 = Ab(4608x512) . Bb(2048x512)^T -> fp32, bf16 MFMA.
// 64x64 tiles (2304 blocks ~ 8/CU), BK=64, stride-72 LDS, XCD swizzle.
// ---------------------------------------------------------------------------
extern "C" __global__ __launch_bounds__(256, 4)
void scan_gemm(const float* __restrict__ ws, float* __restrict__ C)
{
  __shared__ unsigned short Al[64 * 72];
  __shared__ unsigned short Bl[64 * 72];
  const unsigned short* Ab = (const unsigned short*)(ws + ABOFF);
  const unsigned short* Bb = (const unsigned short*)(ws + BBOFF);

  const int tid = threadIdx.x;
  int bid = blockIdx.x;                        // 2304 blocks, %8==0 -> simple swizzle
  bid = (bid & 7) * 288 + (bid >> 3);
  const int m0 = (bid >> 5) * 64;              // 72 m-blocks
  const int n0 = (bid & 31) * 64;              // 32 n-blocks
  const int lane = tid & 63, wave = tid >> 6;
  const int wm = wave >> 1, wn = wave & 1;
  const int lr = lane & 15, lk = lane >> 4;
  const int sr = tid >> 2, sq = tid & 3;       // staging: row, 16-elem quarter

  const unsigned short* gA = Ab + (size_t)(m0 + sr) * Dn + sq * 16;
  const unsigned short* gB = Bb + (size_t)(n0 + sr) * Dn + sq * 16;
  unsigned short* swA = &Al[sr * 72 + sq * 16];
  unsigned short* swB = &Bl[sr * 72 + sq * 16];

  f32x4 acc[2][2];
  #pragma unroll
  for (int x = 0; x < 2; ++x)
    #pragma unroll
    for (int y = 0; y < 2; ++y) acc[x][y] = {0.f, 0.f, 0.f, 0.f};

  for (int k0 = 0; k0 < Dn; k0 += 64) {
    short8 a0 = *reinterpret_cast<const short8*>(gA + k0);
    short8 a1 = *reinterpret_cast<const short8*>(gA + k0 + 8);
    short8 b0 = *reinterpret_cast<const short8*>(gB + k0);
    short8 b1 = *reinterpret_cast<const short8*>(gB + k0 + 8);
    __syncthreads();                           // prior K-step's ds_reads done
    *reinterpret_cast<short8*>(swA)     = a0;
    *reinterpret_cast<short8*>(swA + 8) = a1;
    *reinterpret_cast<short8*>(swB)     = b0;
    *reinterpret_cast<short8*>(swB + 8) = b1;
    __syncthreads();
    #pragma unroll
    for (int ks = 0; ks < 2; ++ks) {
      short8 af[2], bf[2];
      #pragma unroll
      for (int x = 0; x < 2; ++x)
        af[x] = *reinterpret_cast<const short8*>(&Al[(wm * 32 + x * 16 + lr) * 72 + ks * 32 + lk * 8]);
      #pragma unroll
      for (int y = 0; y < 2; ++y)
        bf[y] = *reinterpret_cast<const short8*>(&Bl[(wn * 32 + y * 16 + lr) * 72 + ks * 32 + lk * 8]);
      #pragma unroll
      for (int x = 0; x < 2; ++x)
        #pragma unroll
        for (int y = 0; y < 2; ++y)
          acc[x][y] = __builtin_amdgcn_mfma_f32_16x16x32_bf16(af[x], bf[y], acc[x][y], 0, 0, 0);
    }
  }

  const int orow = m0 + wm * 32 + lk * 4;
  const int ocol = n0 + wn * 32 + lr;
  #pragma unroll
  for (int x = 0; x < 2; ++x)
    #pragma unroll
    for (int y = 0; y < 2; ++y)
      #pragma unroll
      for (int j = 0; j < 4; ++j)
        C[(size_t)(orow + x * 16 + j) * Nn + ocol + y * 16] = acc[x][y][j];
}

// ---------------------------------------------------------------------------
// blocks 0..255: half of G[i] = img_i.img_i^T, stored bf16 padded [48][64].
// blocks 256..319: caption sq-norms.
// ---------------------------------------------------------------------------
extern "C" __global__ __launch_bounds__(256, 2)
void scan_prep(const float* __restrict__ images, const float* __restrict__ captions,
               float* __restrict__ ws)
{
  __shared__ float sm[Rn * 132];
  const int tid = threadIdx.x;
  unsigned short* GbAll = (unsigned short*)(ws + GBOFF);
  if (blockIdx.x < 256) {
    const int i = blockIdx.x >> 1, half = blockIdx.x & 1;
    const float* gi = images + (size_t)i * Rn * Dn;
    unsigned short* gb = GbAll + (size_t)i * 48 * 64;
    float acc[3] = {0.f, 0.f, 0.f};
    for (int ch = 0; ch < 4; ++ch) {
      __syncthreads();
      #pragma unroll
      for (int t = 0; t < 5; ++t) {
        int idx = tid + t * 256;
        if (idx < Rn * 32) {
          int r = idx >> 5, d4 = idx & 31;
          *reinterpret_cast<float4*>(&sm[r * 132 + d4 * 4]) =
            *reinterpret_cast<const float4*>(gi + r * Dn + ch * 128 + d4 * 4);
        }
      }
      __syncthreads();
      #pragma unroll
      for (int q = 0; q < 3; ++q) {
        int eo = tid + q * 256;
        if (eo < 648) {
          int e = half * 648 + eo;
          int r = e / Rn, rp = e - r * Rn;
          float s = 0.f;
          for (int s4 = 0; s4 < 32; ++s4)
            s += dot4(*reinterpret_cast<const float4*>(&sm[r * 132 + s4 * 4]),
                      *reinterpret_cast<const float4*>(&sm[rp * 132 + s4 * 4]));
          acc[q] += s;
        }
      }
    }
    #pragma unroll
    for (int q = 0; q < 3; ++q) {
      int eo = tid + q * 256;
      if (eo < 648) {
        int e = half * 648 + eo;
        int r = e / Rn, rp = e - r * Rn;
        gb[r * 64 + rp] = f2bf(acc[q]);
      }
    }
    for (int idx = tid; idx < 18 * 28; idx += 256) {
      int rr = half * 18 + idx / 28, cc = 36 + idx % 28;
      gb[rr * 64 + cc] = 0;
    }
    for (int idx = tid; idx < 6 * 64; idx += 256) {
      int rr = 36 + half * 6 + (idx >> 6);
      gb[rr * 64 + (idx & 63)] = 0;
    }
  } else {
    const int c = blockIdx.x - 256;
    const float* gc = captions + (size_t)c * Ln * Dn;
    const int l = tid >> 3, p = tid & 7;
    float s = 0.f;
    #pragma unroll
    for (int t = 0; t < 16; ++t) {
      float4 v = *reinterpret_cast<const float4*>(gc + l * Dn + p * 64 + t * 4);
      s += dot4(v, v);
    }
    s += __shfl_xor(s, 1, 64); s += __shfl_xor(s, 2, 64); s += __shfl_xor(s, 4, 64);
    if (p == 0) ws[CNOFF + c * Ln + l] = s;
  }
}

// ---------------------------------------------------------------------------
// Per (i,c): leaky/mask/norm/softmax, wn via MFMA. One 256-thread block.
// ---------------------------------------------------------------------------
extern "C" __global__ __launch_bounds__(256, 2)
void scan_main(const float* __restrict__ ws, const int* __restrict__ cap_lens,
               float* __restrict__ out)
{
  __shared__ float sS0[Rn * Ln];
  __shared__ float sP[Rn * 33];
  __shared__ unsigned short sET[32 * 72];
  __shared__ float sredA[256];
  __shared__ float sredB[256];
  __shared__ float sredC[256];
  __shared__ float sredW[4][20];
  __shared__ float srown[Rn];
  __shared__ float scn[Ln];

  const int tid = threadIdx.x;
  const int c = blockIdx.x & (Cn - 1);
  const int i = blockIdx.x >> 6;
  const int len = cap_lens[c];
  const float* gS0 = ws + (size_t)(i * Rn) * Nn + c * Ln;
  const unsigned short* Gb = (const unsigned short*)(ws + GBOFF) + (size_t)i * 48 * 64;

  #pragma unroll
  for (int t = 0; t < 2; ++t) {
    int idx = tid + t * 256;
    if (idx < Rn * 8) {
      int r = idx >> 3, q = idx & 7;
      *reinterpret_cast<float4*>(&sS0[r * Ln + q * 4]) =
        *reinterpret_cast<const float4*>(gS0 + (size_t)r * Nn + q * 4);
    }
  }
  for (int idx = tid; idx < (32 * 72) / 2; idx += 256)
    reinterpret_cast<unsigned*>(sET)[idx] = 0;
  if (tid < Ln) scn[tid] = ws[CNOFF + c * Ln + tid];
  __syncthreads();

  #pragma unroll
  for (int t = 0; t < 5; ++t) {
    int idx = tid + t * 256;
    if (idx < Rn * Ln) {
      int r = idx >> 5, l = idx & 31;
      float s0 = sS0[idx];
      float s = s0 > 0.f ? s0 : SLOPE * s0;
      if (l >= len) s = 0.f;
      sP[r * 33 + l] = s;
    }
  }
  __syncthreads();

  if (tid < 144) {
    int p = tid & 3, r = tid >> 2;
    float a2 = 0.f;
    #pragma unroll
    for (int j = 0; j < 8; ++j) {
      float v = sP[r * 33 + p + 4 * j];
      a2 = fmaf(v, v, a2);
    }
    a2 += __shfl_xor(a2, 1, 64);
    a2 += __shfl_xor(a2, 2, 64);
    if (p == 0) srown[r] = sqrtf(a2) + EPSf;
  }
  __syncthreads();

  const int l = tid & 31, rg = tid >> 5;
  float z[5];
  float pm = -1e30f;
  #pragma unroll
  for (int k = 0; k < 5; ++k) {
    int r = rg + 8 * k;
    if (r < Rn) {
      float zz = LSM * sP[r * 33 + l] / srown[r];
      z[k] = zz;
      pm = fmaxf(pm, zz);
    } else z[k] = -1e30f;
  }
  sredA[tid] = pm;
  __syncthreads();

  float m = -1e30f;
  #pragma unroll
  for (int g = 0; g < 8; ++g) m = fmaxf(m, sredA[g * 32 + l]);
  float es = 0.f, nump = 0.f;
  #pragma unroll
  for (int k = 0; k < 5; ++k) {
    int r = rg + 8 * k;
    if (r < Rn) {
      float e = expf(z[k] - m);
      es += e;
      nump = fmaf(e, sS0[r * Ln + l], nump);
      sET[l * 72 + r] = f2bf(e);
    }
  }
  sredB[tid] = es;
  sredC[tid] = nump;
  __syncthreads();

  {
    const int lane = tid & 63, wv = tid >> 6;
    const int lr = lane & 15, lk = lane >> 4;
    const int nt = wv & 1;
    const unsigned short* bcol = &sET[(nt * 16 + lr) * 72];
    float wnp = 0.f;
    const int nm = (wv >> 1) ? 1 : 2;
    for (int t = 0; t < nm; ++t) {
      const int mt = (wv >> 1) ? 1 : (t == 0 ? 0 : 2);
      f32x4 acc = {0.f, 0.f, 0.f, 0.f};
      #pragma unroll
      for (int ks = 0; ks < 2; ++ks) {
        short8 afr = *reinterpret_cast<const short8*>(Gb + (mt * 16 + lr) * 64 + ks * 32 + lk * 8);
        short8 bfr = *reinterpret_cast<const short8*>(bcol + ks * 32 + lk * 8);
        acc = __builtin_amdgcn_mfma_f32_16x16x32_bf16(afr, bfr, acc, 0, 0, 0);
      }
      #pragma unroll
      for (int j = 0; j < 4; ++j) {
        int row = mt * 16 + lk * 4 + j;
        if (row < Rn) wnp = fmaf(acc[j], bf2f(bcol[row]), wnp);
      }
    }
    wnp += __shfl_xor(wnp, 16, 64);
    wnp += __shfl_xor(wnp, 32, 64);
    if (lk == 0) sredW[wv][lr] = wnp;
  }
  __syncthreads();

  if (tid < Ln) {
    float esum = 0.f, num = 0.f;
    #pragma unroll
    for (int g = 0; g < 8; ++g) {
      esum += sredB[g * 32 + tid];
      num  += sredC[g * 32 + tid];
    }
    float wn = (tid < 16) ? (sredW[0][tid] + sredW[2][tid])
                          : (sredW[1][tid - 16] + sredW[3][tid - 16]);
    float inv = 1.f / esum;
    num *= inv;
    wn = fmaxf(wn, 0.f) * inv * inv;
    float den = fmaxf(sqrtf(scn[tid]), EPSf) * fmaxf(sqrtf(wn), EPSf);
    float sc = (tid < len) ? (num / den) * LLSE : -INFINITY;
    float mx = sc;
    #pragma unroll
    for (int k = 1; k < 32; k <<= 1) mx = fmaxf(mx, __shfl_xor(mx, k, 64));
    float e = expf(sc - mx);
    #pragma unroll
    for (int k = 1; k < 32; k <<= 1) e += __shfl_xor(e, k, 64);
    if (tid == 0) out[i * Cn + c] = (mx + logf(e)) / LLSE;
  }
}

extern "C" void kernel_launch(void* const* d_in, const int* in_sizes, int n_in,
                              void* d_out, int out_size, void* d_ws, size_t ws_size,
                              hipStream_t stream) {
  const float* images   = (const float*)d_in[0];
  const float* captions = (const float*)d_in[1];
  const int*   cap_lens = (const int*)d_in[2];
  float* out = (float*)d_out;
  float* ws  = (float*)d_ws;
  if (ws_size < WSFLOATS * sizeof(float)) return;

  hipLaunchKernelGGL(scan_cvt, dim3((Mn * Dn + Nn * Dn) / (256 * 8)), dim3(256), 0, stream,
                     images, captions, ws);
  hipLaunchKernelGGL(scan_prep, dim3(320), dim3(256), 0, stream,
                     images, captions, ws);
  hipLaunchKernelGGL(scan_gemm, dim3(2304), dim3(256), 0, stream, ws, ws);
  hipLaunchKernelGGL(scan_main, dim3(In * Cn), dim3(256), 0, stream,
                     ws, cap_lens, out);
}

// Round 7
// 67.286 us; speedup vs baseline: 18.9696x; 1.1465x over previous
//
#include <hip/hip_runtime.h>
#include <math.h>

constexpr int In = 128, Rn = 36, Cn = 64, Ln = 32, Dn = 512;
constexpr int Mn = In * Rn;              // 4608
constexpr int Nn = Cn * Ln;              // 2048
// ws layout (float units)
constexpr size_t ABOFF = 0;                            // images bf16 (Mn*Dn u16)
constexpr size_t BBOFF = (size_t)Mn * Dn / 2;          // captions bf16
constexpr size_t GBOFF = BBOFF + (size_t)Nn * Dn / 2;  // Gb bf16 [In][48][64]
constexpr size_t CNOFF = GBOFF + (size_t)In * 48 * 64 / 2;
constexpr size_t WSFLOATS = CNOFF + (size_t)Cn * Ln;   // ~7.6 MB
constexpr float EPSf = 1e-8f, LLSE = 6.0f, LSM = 9.0f, SLOPE = 0.1f;

using short8 = __attribute__((ext_vector_type(8))) short;
using f32x4  = __attribute__((ext_vector_type(4))) float;

__device__ __forceinline__ float dot4(float4 a, float4 b) {
  return a.x * b.x + a.y * b.y + a.z * b.z + a.w * b.w;
}

__device__ __forceinline__ unsigned short f2bf(float x) {   // RNE
  union { float f; unsigned u; } v; v.f = x;
  unsigned r = v.u + 0x7fffu + ((v.u >> 16) & 1u);
  return (unsigned short)(r >> 16);
}

__device__ __forceinline__ short8 pack8(float4 u, float4 v) {
  short8 s;
  s[0] = (short)f2bf(u.x); s[1] = (short)f2bf(u.y); s[2] = (short)f2bf(u.z); s[3] = (short)f2bf(u.w);
  s[4] = (short)f2bf(v.x); s[5] = (short)f2bf(v.y); s[6] = (short)f2bf(v.z); s[7] = (short)f2bf(v.w);
  return s;
}

// ---------------------------------------------------------------------------
// fp32 -> bf16 one-shot conversion of images+captions into ws. grid 1664.
// ---------------------------------------------------------------------------
extern "C" __global__ __launch_bounds__(256, 2)
void scan_cvt(const float* __restrict__ imgs, const float* __restrict__ caps,
              float* __restrict__ ws)
{
  const int chunk = blockIdx.x * 256 + threadIdx.x;
  const float* src;
  unsigned short* dst;
  size_t off;
  if (chunk < (Mn * Dn) / 8) {
    src = imgs; dst = (unsigned short*)(ws + ABOFF); off = (size_t)chunk * 8;
  } else {
    src = caps; dst = (unsigned short*)(ws + BBOFF);
    off = (size_t)(chunk - (Mn * Dn) / 8) * 8;
  }
  float4 u = *reinterpret_cast<const float4*>(src + off);
  float4 v = *reinterpret_cast<const float4*>(src + off + 4);
  *reinterpret_cast<short8*>(dst + off) = pack8(u, v);
}

// ---------------------------------------------------------------------------
// blocks 0..255: half of G[i] = img_i.img_i^T, stored bf16 padded [48][64].
// blocks 256..319: caption sq-norms (fp32).
// ---------------------------------------------------------------------------
extern "C" __global__ __launch_bounds__(256, 2)
void scan_prep(const float* __restrict__ images, const float* __restrict__ captions,
               float* __restrict__ ws)
{
  __shared__ float sm[Rn * 132];
  const int tid = threadIdx.x;
  unsigned short* GbAll = (unsigned short*)(ws + GBOFF);
  if (blockIdx.x < 256) {
    const int i = blockIdx.x >> 1, half = blockIdx.x & 1;
    const float* gi = images + (size_t)i * Rn * Dn;
    unsigned short* gb = GbAll + (size_t)i * 48 * 64;
    float acc[3] = {0.f, 0.f, 0.f};
    for (int ch = 0; ch < 4; ++ch) {
      __syncthreads();
      #pragma unroll
      for (int t = 0; t < 5; ++t) {
        int idx = tid + t * 256;
        if (idx < Rn * 32) {
          int r = idx >> 5, d4 = idx & 31;
          *reinterpret_cast<float4*>(&sm[r * 132 + d4 * 4]) =
            *reinterpret_cast<const float4*>(gi + r * Dn + ch * 128 + d4 * 4);
        }
      }
      __syncthreads();
      #pragma unroll
      for (int q = 0; q < 3; ++q) {
        int eo = tid + q * 256;
        if (eo < 648) {
          int e = half * 648 + eo;
          int r = e / Rn, rp = e - r * Rn;
          float s = 0.f;
          for (int s4 = 0; s4 < 32; ++s4)
            s += dot4(*reinterpret_cast<const float4*>(&sm[r * 132 + s4 * 4]),
                      *reinterpret_cast<const float4*>(&sm[rp * 132 + s4 * 4]));
          acc[q] += s;
        }
      }
    }
    #pragma unroll
    for (int q = 0; q < 3; ++q) {
      int eo = tid + q * 256;
      if (eo < 648) {
        int e = half * 648 + eo;
        int r = e / Rn, rp = e - r * Rn;
        gb[r * 64 + rp] = f2bf(acc[q]);
      }
    }
    for (int idx = tid; idx < 18 * 28; idx += 256) {
      int rr = half * 18 + idx / 28, cc = 36 + idx % 28;
      gb[rr * 64 + cc] = 0;
    }
    for (int idx = tid; idx < 6 * 64; idx += 256) {
      int rr = 36 + half * 6 + (idx >> 6);
      gb[rr * 64 + (idx & 63)] = 0;
    }
  } else {
    const int c = blockIdx.x - 256;
    const float* gc = captions + (size_t)c * Ln * Dn;
    const int l = tid >> 3, p = tid & 7;
    float s = 0.f;
    #pragma unroll
    for (int t = 0; t < 16; ++t) {
      float4 v = *reinterpret_cast<const float4*>(gc + l * Dn + p * 64 + t * 4);
      s += dot4(v, v);
    }
    s += __shfl_xor(s, 1, 64); s += __shfl_xor(s, 2, 64); s += __shfl_xor(s, 4, 64);
    if (p == 0) ws[CNOFF + c * Ln + l] = s;
  }
}

// ---------------------------------------------------------------------------
// Fused: block = 1 image x 4 captions (wave = caption). S0 stays in MFMA accs;
// epilogue does leaky/mask/norm/softmax/num, wn via second MFMA vs Gb, LSE.
// Grid 2048, XCD-chunked swizzle.
// ---------------------------------------------------------------------------
extern "C" __global__ __launch_bounds__(256, 2)
void scan_fused(const float* __restrict__ ws, const int* __restrict__ cap_lens,
                float* __restrict__ out)
{
  __shared__ unsigned short Al[48 * 72];    //  6.9 KB
  __shared__ unsigned short Bl[128 * 72];   // 18.4 KB (reused for E^T per wave)
  const unsigned short* Ab = (const unsigned short*)(ws + ABOFF);
  const unsigned short* Bb = (const unsigned short*)(ws + BBOFF);
  const unsigned short* GbAll = (const unsigned short*)(ws + GBOFF);
  const float* cnArr = ws + CNOFF;

  const int tid = threadIdx.x;
  int bid = blockIdx.x;                      // 2048 blocks; 8 chunks of 256
  bid = (bid & 7) * 256 + (bid >> 3);
  const int ig = bid >> 4;                   // image
  const int cg = bid & 15;                   // caption group (4 captions)
  const int lane = tid & 63, wv = tid >> 6;
  const int lr = lane & 15, lk = lane >> 4;
  const int cap = cg * 4 + wv;
  const int len = cap_lens[cap];

  // staging coords
  const int ar = tid >> 2, aq = tid & 3;     // A: 48 rows x 4 quarters (t<192)
  const int br = tid >> 1, bh = tid & 1;     // B: 128 rows x 2 halves

  const unsigned short* gA = Ab + ((size_t)ig * 36 + (ar < 36 ? ar : 0)) * Dn + aq * 16;
  const unsigned short* gB = Bb + ((size_t)(cg * 128) + br) * Dn + bh * 32;
  const bool aValid = (tid < 192) && (ar < 36);
  const bool aPad   = (tid < 192) && (ar >= 36);

  f32x4 acc[3][2];
  #pragma unroll
  for (int x = 0; x < 3; ++x)
    #pragma unroll
    for (int y = 0; y < 2; ++y) acc[x][y] = {0.f, 0.f, 0.f, 0.f};

  for (int k0 = 0; k0 < Dn; k0 += 64) {
    short8 a0 = {0,0,0,0,0,0,0,0}, a1 = {0,0,0,0,0,0,0,0};
    if (aValid) {
      a0 = *reinterpret_cast<const short8*>(gA + k0);
      a1 = *reinterpret_cast<const short8*>(gA + k0 + 8);
    }
    short8 b0 = *reinterpret_cast<const short8*>(gB + k0);
    short8 b1 = *reinterpret_cast<const short8*>(gB + k0 + 8);
    short8 b2 = *reinterpret_cast<const short8*>(gB + k0 + 16);
    short8 b3 = *reinterpret_cast<const short8*>(gB + k0 + 24);
    __syncthreads();                          // prior K-step's ds_reads done
    if (aValid || aPad) {
      *reinterpret_cast<short8*>(&Al[ar * 72 + aq * 16])     = a0;
      *reinterpret_cast<short8*>(&Al[ar * 72 + aq * 16 + 8]) = a1;
    }
    {
      unsigned short* w = &Bl[br * 72 + bh * 32];
      *reinterpret_cast<short8*>(w)      = b0;
      *reinterpret_cast<short8*>(w + 8)  = b1;
      *reinterpret_cast<short8*>(w + 16) = b2;
      *reinterpret_cast<short8*>(w + 24) = b3;
    }
    __syncthreads();
    #pragma unroll
    for (int ks = 0; ks < 2; ++ks) {
      short8 af[3], bf[2];
      #pragma unroll
      for (int x = 0; x < 3; ++x)
        af[x] = *reinterpret_cast<const short8*>(&Al[(x * 16 + lr) * 72 + ks * 32 + lk * 8]);
      #pragma unroll
      for (int y = 0; y < 2; ++y)
        bf[y] = *reinterpret_cast<const short8*>(&Bl[(wv * 32 + y * 16 + lr) * 72 + ks * 32 + lk * 8]);
      #pragma unroll
      for (int x = 0; x < 3; ++x)
        #pragma unroll
        for (int y = 0; y < 2; ++y)
          acc[x][y] = __builtin_amdgcn_mfma_f32_16x16x32_bf16(af[x], bf[y], acc[x][y], 0, 0, 0);
    }
  }

  // prefetch G fragments (L2) + caption norms while VALU epilogue runs
  const unsigned short* Gb = GbAll + (size_t)ig * 48 * 64;
  short8 gfr[3][2];
  #pragma unroll
  for (int x = 0; x < 3; ++x)
    #pragma unroll
    for (int ks = 0; ks < 2; ++ks)
      gfr[x][ks] = *reinterpret_cast<const short8*>(Gb + (x * 16 + lr) * 64 + ks * 32 + lk * 8);
  const float cn0 = cnArr[cap * 32 + lr];
  const float cn1 = cnArr[cap * 32 + 16 + lr];

  // ---- epilogue (per wave = per caption) ----
  // acc[x][y][j] = S0raw at row 16x+lk*4+j, col 16y+lr (rows>=36 are exact 0)
  float s[3][2][4];
  #pragma unroll
  for (int x = 0; x < 3; ++x)
    #pragma unroll
    for (int y = 0; y < 2; ++y) {
      const int l = y * 16 + lr;
      #pragma unroll
      for (int j = 0; j < 4; ++j) {
        float v = acc[x][y][j];
        v = v > 0.f ? v : SLOPE * v;
        if (l >= len) v = 0.f;
        s[x][y][j] = v;
      }
    }

  // row l2-norms (per row: sum over 32 cols = 2 local + 16 lr-lanes)
  float zinv[3][4];
  #pragma unroll
  for (int x = 0; x < 3; ++x)
    #pragma unroll
    for (int j = 0; j < 4; ++j) {
      float t = s[x][0][j] * s[x][0][j] + s[x][1][j] * s[x][1][j];
      t += __shfl_xor(t, 1, 64); t += __shfl_xor(t, 2, 64);
      t += __shfl_xor(t, 4, 64); t += __shfl_xor(t, 8, 64);
      zinv[x][j] = LSM / (sqrtf(t) + EPSf);
    }

  // z (overwrite s), masked col-max over valid rows (<36)
  const bool x2ok = (lk == 0);               // x=2 rows 32..35 only for lk==0
  float mcol[2] = {-1e30f, -1e30f};
  #pragma unroll
  for (int x = 0; x < 3; ++x)
    #pragma unroll
    for (int y = 0; y < 2; ++y)
      #pragma unroll
      for (int j = 0; j < 4; ++j) {
        float zz = s[x][y][j] * zinv[x][j];
        s[x][y][j] = zz;
        if (x < 2 || x2ok) mcol[y] = fmaxf(mcol[y], zz);
      }
  #pragma unroll
  for (int y = 0; y < 2; ++y) {
    mcol[y] = fmaxf(mcol[y], __shfl_xor(mcol[y], 16, 64));
    mcol[y] = fmaxf(mcol[y], __shfl_xor(mcol[y], 32, 64));
  }

  // e = exp(z - m); esum, num fused
  float e[3][2][4];
  float esum[2] = {0.f, 0.f}, num[2] = {0.f, 0.f};
  #pragma unroll
  for (int x = 0; x < 3; ++x)
    #pragma unroll
    for (int y = 0; y < 2; ++y)
      #pragma unroll
      for (int j = 0; j < 4; ++j) {
        float ev = (x < 2 || x2ok) ? expf(s[x][y][j] - mcol[y]) : 0.f;
        e[x][y][j] = ev;
        esum[y] += ev;
        num[y] = fmaf(ev, acc[x][y][j], num[y]);
      }
  #pragma unroll
  for (int y = 0; y < 2; ++y) {
    esum[y] += __shfl_xor(esum[y], 16, 64); esum[y] += __shfl_xor(esum[y], 32, 64);
    num[y]  += __shfl_xor(num[y], 16, 64);  num[y]  += __shfl_xor(num[y], 32, 64);
  }

  // E^T (bf16) into this wave's private Bl region: [l(32)][r pad 64], stride 72
  unsigned short* ET = &Bl[(wv * 32) * 72];
  {
    // zero r = 48..63 (one short8 per lane)
    const int zl = lane >> 1, zs = lane & 1;
    short8 zero = {0,0,0,0,0,0,0,0};
    *reinterpret_cast<short8*>(&ET[zl * 72 + 48 + zs * 8]) = zero;
  }
  #pragma unroll
  for (int x = 0; x < 3; ++x)
    #pragma unroll
    for (int y = 0; y < 2; ++y)
      #pragma unroll
      for (int j = 0; j < 4; ++j)
        ET[(y * 16 + lr) * 72 + (x * 16 + lk * 4 + j)] = f2bf(e[x][y][j]);
  __syncthreads();

  // V = G.E via MFMA: identical fragment distribution to e -> in-lane dot
  f32x4 vac[3][2];
  #pragma unroll
  for (int x = 0; x < 3; ++x)
    #pragma unroll
    for (int y = 0; y < 2; ++y) vac[x][y] = {0.f, 0.f, 0.f, 0.f};
  #pragma unroll
  for (int ks = 0; ks < 2; ++ks) {
    short8 efr[2];
    #pragma unroll
    for (int y = 0; y < 2; ++y)
      efr[y] = *reinterpret_cast<const short8*>(&ET[(y * 16 + lr) * 72 + ks * 32 + lk * 8]);
    #pragma unroll
    for (int x = 0; x < 3; ++x)
      #pragma unroll
      for (int y = 0; y < 2; ++y)
        vac[x][y] = __builtin_amdgcn_mfma_f32_16x16x32_bf16(gfr[x][ks], efr[y], vac[x][y], 0, 0, 0);
  }
  float wn[2] = {0.f, 0.f};
  #pragma unroll
  for (int x = 0; x < 3; ++x)
    #pragma unroll
    for (int y = 0; y < 2; ++y)
      #pragma unroll
      for (int j = 0; j < 4; ++j)
        wn[y] = fmaf(e[x][y][j], vac[x][y][j], wn[y]);
  #pragma unroll
  for (int y = 0; y < 2; ++y) {
    wn[y] += __shfl_xor(wn[y], 16, 64); wn[y] += __shfl_xor(wn[y], 32, 64);
  }

  // cosine + masked LSE over the caption's 32 cols
  float sc[2];
  #pragma unroll
  for (int y = 0; y < 2; ++y) {
    const int l = y * 16 + lr;
    const float cn = y ? cn1 : cn0;
    float inv = 1.f / esum[y];
    float nm = num[y] * inv;
    float w = fmaxf(wn[y], 0.f) * inv * inv;
    float den = fmaxf(sqrtf(cn), EPSf) * fmaxf(sqrtf(w), EPSf);
    sc[y] = (l < len) ? (nm / den) * LLSE : -INFINITY;
  }
  float mx = fmaxf(sc[0], sc[1]);
  mx = fmaxf(mx, __shfl_xor(mx, 1, 64)); mx = fmaxf(mx, __shfl_xor(mx, 2, 64));
  mx = fmaxf(mx, __shfl_xor(mx, 4, 64)); mx = fmaxf(mx, __shfl_xor(mx, 8, 64));
  float ex = expf(sc[0] - mx) + expf(sc[1] - mx);
  ex += __shfl_xor(ex, 1, 64); ex += __shfl_xor(ex, 2, 64);
  ex += __shfl_xor(ex, 4, 64); ex += __shfl_xor(ex, 8, 64);
  if (lane == 0) out[ig * Cn + cap] = (mx + logf(ex)) / LLSE;
}

extern "C" void kernel_launch(void* const* d_in, const int* in_sizes, int n_in,
                              void* d_out, int out_size, void* d_ws, size_t ws_size,
                              hipStream_t stream) {
  const float* images   = (const float*)d_in[0];
  const float* captions = (const float*)d_in[1];
  const int*   cap_lens = (const int*)d_in[2];
  float* out = (float*)d_out;
  float* ws  = (float*)d_ws;
  if (ws_size < WSFLOATS * sizeof(float)) return;

  hipLaunchKernelGGL(scan_cvt, dim3((Mn * Dn + Nn * Dn) / (256 * 8)), dim3(256), 0, stream,
                     images, captions, ws);
  hipLaunchKernelGGL(scan_prep, dim3(320), dim3(256), 0, stream,
                     images, captions, ws);
  hipLaunchKernelGGL(scan_fused, dim3(In * 16), dim3(256), 0, stream,
                     ws, cap_lens, out);
}